// Round 1
// baseline (718.735 us; speedup 1.0000x reference)
//
#include <hip/hip_runtime.h>
#include <hip/hip_bf16.h>
#include <cstdint>

// Problem constants: B=64, T=512, E=256, H=128, 4H=512.
#define BB 64
#define TT 512
#define EE 256
#define HH 128
#define G4 512

typedef _Float16 half2_t __attribute__((ext_vector_type(2)));
typedef _Float16 f16x4 __attribute__((ext_vector_type(4)));
typedef _Float16 f16x8 __attribute__((ext_vector_type(8)));
typedef float f32x4 __attribute__((ext_vector_type(4)));

__device__ __forceinline__ float fdot2f(half2_t a, half2_t b, float c) {
#if defined(__has_builtin)
#if __has_builtin(__builtin_amdgcn_fdot2)
  return __builtin_amdgcn_fdot2(a, b, c, false);
#else
  return c + (float)a[0] * (float)b[0] + (float)a[1] * (float)b[1];
#endif
#else
  return c + (float)a[0] * (float)b[0] + (float)a[1] * (float)b[1];
#endif
}

__device__ __forceinline__ float rcp_(float x) { return __builtin_amdgcn_rcpf(x); }
__device__ __forceinline__ float sigmoid_(float x) {
  return rcp_(1.f + __expf(-x));
}
__device__ __forceinline__ float tanh_(float x) {
  float ax = fabsf(x);
  float e = __expf(-2.f * ax);             // in (0,1], no overflow ever
  float r = (1.f - e) * rcp_(1.f + e);
  return copysignf(r, x);
}

// ---------------------------------------------------------------------------
// Kernel A: trans = row-softmax(transition); W16 = (f16)W_ih
// grid 256 x 128 threads. blocks 0..127: softmax row; 128..255: W_ih convert.
// ---------------------------------------------------------------------------
__global__ __launch_bounds__(128) void prep_kernel(
    const float* __restrict__ transition, const float* __restrict__ W_ih,
    float* __restrict__ trans, _Float16* __restrict__ W16) {
  const int bid = blockIdx.x, t = threadIdx.x;
  if (bid < 128) {
    __shared__ float red[2];
    float v = transition[bid * HH + t];
    float m = v;
#pragma unroll
    for (int s = 32; s >= 1; s >>= 1) m = fmaxf(m, __shfl_xor(m, s));
    if ((t & 63) == 0) red[t >> 6] = m;
    __syncthreads();
    m = fmaxf(red[0], red[1]);
    float e = __expf(v - m);
    float s = e;
#pragma unroll
    for (int k = 32; k >= 1; k >>= 1) s += __shfl_xor(s, k);
    __syncthreads();  // protect red before reuse
    if ((t & 63) == 0) red[t >> 6] = s;
    __syncthreads();
    trans[bid * HH + t] = e * rcp_(red[0] + red[1]);
  } else {
    const int base = (bid - 128) * 1024 + t * 8;  // 131072 total elems
    float4 v0 = *(const float4*)(W_ih + base);
    float4 v1 = *(const float4*)(W_ih + base + 4);
    f16x8 h;
    h[0] = (_Float16)v0.x; h[1] = (_Float16)v0.y;
    h[2] = (_Float16)v0.z; h[3] = (_Float16)v0.w;
    h[4] = (_Float16)v1.x; h[5] = (_Float16)v1.y;
    h[6] = (_Float16)v1.z; h[7] = (_Float16)v1.w;
    *(f16x8*)(W16 + base) = h;
  }
}

// ---------------------------------------------------------------------------
// Kernel B: precomp[m][j] = sum_e inputs[m][e]*W_ih[j][e] + b_ih[j] + b_hh[j]
// M=32768, N=512, K=256.  MFMA f16 16x16x32.  BM=64 (LDS-staged), BN=256
// (4 waves x 64 cols, B-frags straight from L2-resident W16).
// grid (512, 2) x 256 threads.
// ---------------------------------------------------------------------------
__global__ __launch_bounds__(256) void gemm_in(
    const float* __restrict__ A, const _Float16* __restrict__ W16,
    const float* __restrict__ b_ih, const float* __restrict__ b_hh,
    float* __restrict__ out) {
  __shared__ _Float16 As[64][264];  // K=256 + 8 pad (16B-aligned rows)
  const int t = threadIdx.x;
  const int m0 = blockIdx.x * 64;
  const int n0 = blockIdx.y * 256;
  {
    const int c4 = t & 63, r0 = t >> 6;
#pragma unroll
    for (int p = 0; p < 16; ++p) {
      const int row = r0 + 4 * p;
      float4 v = *(const float4*)(A + (size_t)(m0 + row) * EE + c4 * 4);
      f16x4 h;
      h[0] = (_Float16)v.x; h[1] = (_Float16)v.y;
      h[2] = (_Float16)v.z; h[3] = (_Float16)v.w;
      *(f16x4*)&As[row][c4 * 4] = h;
    }
  }
  __syncthreads();
  const int w = t >> 6, L = t & 63;
  const int lrow = L & 15, quad = L >> 4, lk = quad * 8;
  f32x4 acc[4][4] = {};
  const _Float16* Wbase = W16 + (size_t)(n0 + w * 64) * EE;
#pragma unroll
  for (int kc = 0; kc < 8; ++kc) {
    f16x8 a[4], bf[4];
#pragma unroll
    for (int mf = 0; mf < 4; ++mf)
      a[mf] = *(const f16x8*)&As[mf * 16 + lrow][kc * 32 + lk];
#pragma unroll
    for (int nf = 0; nf < 4; ++nf)
      bf[nf] = *(const f16x8*)(Wbase + (size_t)(nf * 16 + lrow) * EE + kc * 32 + lk);
#pragma unroll
    for (int mf = 0; mf < 4; ++mf)
#pragma unroll
      for (int nf = 0; nf < 4; ++nf)
        acc[mf][nf] = __builtin_amdgcn_mfma_f32_16x16x32_f16(a[mf], bf[nf], acc[mf][nf], 0, 0, 0);
  }
#pragma unroll
  for (int nf = 0; nf < 4; ++nf) {
    const int j = n0 + w * 64 + nf * 16 + lrow;  // C/D: col = lane&15
    const float bias = b_ih[j] + b_hh[j];
#pragma unroll
    for (int mf = 0; mf < 4; ++mf) {
#pragma unroll
      for (int r = 0; r < 4; ++r) {  // C/D: row = quad*4 + r
        const int m = m0 + mf * 16 + quad * 4 + r;
        out[(size_t)m * G4 + j] = acc[mf][nf][r] + bias;
      }
    }
  }
}

// ---------------------------------------------------------------------------
// Kernel C: fused LSTM recurrence + per-step softmax + CRF forward + emit.
// One workgroup (512 thr = 8 waves) per batch.
// Restructured vs previous version:
//   * 2 barriers/step (was 3): post-matvec phase runs entirely in wave 0
//     (lane l owns hidden units 2l, 2l+1) so the softmax denominator is a
//     6-level in-wave __shfl_xor reduce — no cross-wave red[] round trip.
//   * CRF running max (mused), pre, and the emission accumulator live in
//     registers; p_lds / pre0[] LDS ping-pongs deleted.  Emission gathered
//     per-lane (unit==label compare), reduced once in the epilogue.
//   * log(S) computed before the cell chain (independent); next-step max
//     proxy broadcast early via __shfl(lgS0,0) so the tail is exp+pack+write.
//   * Recurrent matvec covers the full K=128 (16 float4 chunks of h).
// ---------------------------------------------------------------------------
__global__ __launch_bounds__(512, 2) void lstm_crf(
    const float* __restrict__ precomp, const float* __restrict__ Whh,
    const float* __restrict__ trans, const int* __restrict__ labels,
    float* __restrict__ out_b) {
  const int b = blockIdx.x, t = threadIdx.x;
  __shared__ __align__(16) _Float16 h_lds[HH];
  __shared__ __align__(16) _Float16 E_lds[HH];
  __shared__ __align__(16) float act[G4];
  __shared__ float Spart[4][132];
  __shared__ int lab[TT];

  // --- one-time loads -------------------------------------------------------
  half2_t w[64];  // W_hh[t][0..127] as f16 pairs (full row)
  {
    const float4* wr = (const float4*)(Whh + (size_t)t * HH);
#pragma unroll
    for (int i = 0; i < 32; ++i) {
      float4 v = wr[i];
      half2_t a, c2;
      a[0] = (_Float16)v.x; a[1] = (_Float16)v.y;
      c2[0] = (_Float16)v.z; c2[1] = (_Float16)v.w;
      w[2 * i] = a; w[2 * i + 1] = c2;
    }
  }
  const int q = t >> 7, j = t & 127;
  half2_t et[16];  // exp(trans[q*32 + 2a (+1)][j])
#pragma unroll
  for (int a2 = 0; a2 < 16; ++a2) {
    float e0 = __expf(trans[(q * 32 + 2 * a2) * HH + j]);
    float e1 = __expf(trans[(q * 32 + 2 * a2 + 1) * HH + j]);
    half2_t hh2; hh2[0] = (_Float16)e0; hh2[1] = (_Float16)e1;
    et[a2] = hh2;
  }
  lab[t] = labels[b * TT + t];
  if (t < HH) { h_lds[t] = (_Float16)0.f; E_lds[t] = (_Float16)0.f; }

  // wave-0 per-lane persistent state (units u0 = 2t, u0+1)
  const int u0 = t * 2;
  float tr0x = 0.f, tr0y = 0.f, tr127x = 0.f, tr127y = 0.f;
  if (t < 64) {
    tr0x = trans[u0];
    tr0y = trans[u0 + 1];
    tr127x = trans[127 * HH + u0];
    tr127y = trans[127 * HH + u0 + 1];
  }
  float c0 = 0.f, c1 = 0.f, preA = 0.f, preB = 0.f, mused = 0.f, emit = 0.f;

  const float* pc = precomp + (size_t)b * TT * G4 + t;
  float nxt = pc[0];
  __syncthreads();

#pragma unroll 1
  for (int step = 0; step < TT; ++step) {
    const float cur = nxt;
    if (step < TT - 1) nxt = pc[(size_t)(step + 1) * G4];
    // --- phase 1 (all 512 threads): LSTM gate-row dot + CRF partial dot ----
    float a0 = 0.f, a1 = 0.f;
    const float4* hv = (const float4*)h_lds;
#pragma unroll
    for (int ch = 0; ch < 16; ++ch) {
      float4 hb = hv[ch];  // 8 halves, broadcast read
      a0 = fdot2f(w[4 * ch + 0], __builtin_bit_cast(half2_t, hb.x), a0);
      a1 = fdot2f(w[4 * ch + 1], __builtin_bit_cast(half2_t, hb.y), a1);
      a0 = fdot2f(w[4 * ch + 2], __builtin_bit_cast(half2_t, hb.z), a0);
      a1 = fdot2f(w[4 * ch + 3], __builtin_bit_cast(half2_t, hb.w), a1);
    }
    float s0 = 0.f;
    const float4* ev = (const float4*)E_lds;
#pragma unroll
    for (int ec = 0; ec < 4; ++ec) {
      float4 eb = ev[q * 4 + ec];
      s0 = fdot2f(et[4 * ec + 0], __builtin_bit_cast(half2_t, eb.x), s0);
      s0 = fdot2f(et[4 * ec + 1], __builtin_bit_cast(half2_t, eb.y), s0);
      s0 = fdot2f(et[4 * ec + 2], __builtin_bit_cast(half2_t, eb.z), s0);
      s0 = fdot2f(et[4 * ec + 3], __builtin_bit_cast(half2_t, eb.w), s0);
    }
    const float gate = cur + a0 + a1;
    act[t] = (q == 2) ? tanh_(gate) : sigmoid_(gate);
    Spart[q][j] = s0;
    __syncthreads();  // A
    // --- phase 2 (wave 0 only): cell, softmax, CRF update, all in-wave -----
    if (t < 64) {
      // CRF S + logs first: independent of the cell chain, hides latency
      float S0 = Spart[0][u0] + Spart[1][u0] + Spart[2][u0] + Spart[3][u0];
      float S1 = Spart[0][u0 + 1] + Spart[1][u0 + 1] + Spart[2][u0 + 1] + Spart[3][u0 + 1];
      const int lb = lab[step];
      const float lgS0 = __logf(S0), lgS1 = __logf(S1);
      const float Mnext = (step == 0) ? 0.f : (mused + __shfl(lgS0, 0));
      const float base0 = (step == 0) ? tr0x : (mused + lgS0);
      const float base1 = (step == 0) ? tr0y : (mused + lgS1);
      // LSTM cell update for units u0, u0+1
      float2 I = *(const float2*)&act[u0];
      float2 F = *(const float2*)&act[128 + u0];
      float2 G = *(const float2*)&act[256 + u0];
      float2 O = *(const float2*)&act[384 + u0];
      c0 = F.x * c0 + I.x * G.x;
      c1 = F.y * c1 + I.y * G.y;
      const float h0 = O.x * tanh_(c0), h1 = O.y * tanh_(c1);
      const float e0 = __expf(h0), e1 = __expf(h1);  // |h|<1, no max-sub needed
      float ts = e0 + e1;
#pragma unroll
      for (int s2 = 32; s2 >= 1; s2 >>= 1) ts += __shfl_xor(ts, s2);
      const float rinv = rcp_(ts);
      const float p0 = e0 * rinv, p1 = e1 * rinv;
      emit += (u0 == lb ? p0 : 0.f) + (u0 + 1 == lb ? p1 : 0.f);
      preA = p0 + base0;
      preB = p1 + base1;
      // E = exp(pre - Mnext): Mnext = pre[0]-p[0] -> E in ~[e^-3, e^3], f16-safe
      half2_t Eh;
      Eh[0] = (_Float16)__expf(preA - Mnext);
      Eh[1] = (_Float16)__expf(preB - Mnext);
      *(half2_t*)&E_lds[u0] = Eh;
      half2_t Hh;
      Hh[0] = (_Float16)h0;
      Hh[1] = (_Float16)h1;
      *(half2_t*)&h_lds[u0] = Hh;
      mused = Mnext;
    }
    __syncthreads();  // D
  }
  // --- epilogue (wave 0): Ps = LSE(pre + trans[127]); out_b = Ps - emit ----
  if (t < 64) {
    float v0 = preA + tr127x, v1 = preB + tr127y;
    float m = fmaxf(v0, v1);
#pragma unroll
    for (int s2 = 32; s2 >= 1; s2 >>= 1) m = fmaxf(m, __shfl_xor(m, s2));
    float ex = __expf(v0 - m) + __expf(v1 - m);
    float em = emit;
#pragma unroll
    for (int s2 = 32; s2 >= 1; s2 >>= 1) {
      ex += __shfl_xor(ex, s2);
      em += __shfl_xor(em, s2);
    }
    if (t == 0) out_b[b] = m + __logf(ex) - em;
  }
}

// ---------------------------------------------------------------------------
// Kernel D: total = sum_b out_b[b] - sum_{b,t<511} trans[l_t][l_{t+1}]
// ---------------------------------------------------------------------------
__global__ __launch_bounds__(512) void finalize_kernel(
    const float* __restrict__ trans, const int* __restrict__ labels,
    const float* __restrict__ out_b, float* __restrict__ d_out) {
  const int t = threadIdx.x;
  float a = 0.f;
  if (t < TT - 1) {
    for (int b = 0; b < BB; ++b) {
      const int l0 = labels[b * TT + t];
      const int l1 = labels[b * TT + t + 1];
      a += trans[l0 * HH + l1];
    }
  }
  float x = ((t < BB) ? out_b[t] : 0.f) - a;
  __shared__ float red[8];
#pragma unroll
  for (int s = 32; s >= 1; s >>= 1) x += __shfl_xor(x, s);
  if ((t & 63) == 0) red[t >> 6] = x;
  __syncthreads();
  if (t == 0) {
    float s = 0.f;
#pragma unroll
    for (int i = 0; i < 8; ++i) s += red[i];
    d_out[0] = s;
  }
}

// ---------------------------------------------------------------------------
extern "C" void kernel_launch(void* const* d_in, const int* in_sizes, int n_in,
                              void* d_out, int out_size, void* d_ws, size_t ws_size,
                              hipStream_t stream) {
  const float* inputs = (const float*)d_in[0];      // (64,512,256) f32
  const int* labels = (const int*)d_in[1];          // (64,512) i32
  const float* W_ih = (const float*)d_in[2];        // (512,256) f32
  const float* W_hh = (const float*)d_in[3];        // (512,128) f32
  const float* b_ih = (const float*)d_in[4];        // (512,) f32
  const float* b_hh = (const float*)d_in[5];        // (512,) f32
  const float* transition = (const float*)d_in[6];  // (128,128) f32

  char* ws = (char*)d_ws;
  float* precomp = (float*)ws;                           // 64 MiB
  float* trans = (float*)(ws + 67108864);                // 64 KiB
  _Float16* W16 = (_Float16*)(ws + 67108864 + 65536);    // 256 KiB
  float* out_b = (float*)(ws + 67108864 + 65536 + 262144);

  prep_kernel<<<256, 128, 0, stream>>>(transition, W_ih, trans, W16);
  gemm_in<<<dim3(512, 2), 256, 0, stream>>>(inputs, W16, b_ih, b_hh, precomp);
  lstm_crf<<<64, 512, 0, stream>>>(precomp, W_hh, trans, labels, out_b);
  finalize_kernel<<<1, 512, 0, stream>>>(trans, labels, out_b, (float*)d_out);
}